// Round 1
// baseline (1451.049 us; speedup 1.0000x reference)
//
#include <hip/hip_runtime.h>
#include <cstddef>

#define NN 50000
#define NE 800000
#define KDIM 256

typedef __bf16 bf16x8 __attribute__((ext_vector_type(8)));
typedef float floatx4 __attribute__((ext_vector_type(4)));

__device__ __forceinline__ float bflo2f(unsigned int u) {
    union { unsigned int u; float f; } v; v.u = u << 16; return v.f;
}
__device__ __forceinline__ float bfhi2f(unsigned int u) {
    union { unsigned int u; float f; } v; v.u = u & 0xffff0000u; return v.f;
}
__device__ __forceinline__ unsigned short f2bf(float f) {
    union { float f; unsigned int u; } v; v.f = f;
    unsigned int u = v.u;
    unsigned int r = u + 0x7fffu + ((u >> 16) & 1u);   // RNE
    return (unsigned short)(r >> 16);
}

// ---------------- CSR build ----------------

__global__ void k_count(const int* __restrict__ e0, const int* __restrict__ e1,
                        const int* __restrict__ e2, const int* __restrict__ e3,
                        int* __restrict__ counts) {
    const int* es[4] = {e0, e1, e2, e3};
    int r = blockIdx.y;
    int i = blockIdx.x * blockDim.x + threadIdx.x;
    if (i < NE) {
        int d = es[r][NE + i];
        atomicAdd(&counts[r * NN + d], 1);
    }
}

__global__ void k_deg(const int* __restrict__ counts, float* __restrict__ dinv,
                      float* __restrict__ invdeg, int total) {
    int i = blockIdx.x * blockDim.x + threadIdx.x;
    if (i < total) {
        float d = (float)(counts[i] + 1);
        dinv[i] = rsqrtf(d);
        invdeg[i] = 1.0f / d;
    }
}

#define SCH 256
__global__ void k_scan_a(const int* __restrict__ counts, int* __restrict__ bsum, int n) {
    __shared__ int sd[SCH];
    int r = blockIdx.y, b = blockIdx.x, t = threadIdx.x;
    int i = b * SCH + t;
    int v = (i < n) ? counts[r * n + i] : 0;
    sd[t] = v; __syncthreads();
    for (int o = 1; o < SCH; o <<= 1) {
        int x = (t >= o) ? sd[t - o] : 0; __syncthreads();
        sd[t] += x; __syncthreads();
    }
    if (t == SCH - 1) bsum[r * gridDim.x + b] = sd[t];
}
__global__ void k_scan_b(int* __restrict__ bsum, int nch) {
    __shared__ int sd[SCH];
    int r = blockIdx.y, t = threadIdx.x;
    int v = (t < nch) ? bsum[r * nch + t] : 0;
    sd[t] = v; __syncthreads();
    for (int o = 1; o < SCH; o <<= 1) {
        int x = (t >= o) ? sd[t - o] : 0; __syncthreads();
        sd[t] += x; __syncthreads();
    }
    if (t < nch) bsum[r * nch + t] = sd[t] - v;   // exclusive
}
__global__ void k_scan_c(const int* __restrict__ counts, const int* __restrict__ bsum,
                         int* __restrict__ rowptr, int n, int nch) {
    __shared__ int sd[SCH];
    int r = blockIdx.y, b = blockIdx.x, t = threadIdx.x;
    int i = b * SCH + t;
    int v = (i < n) ? counts[r * n + i] : 0;
    sd[t] = v; __syncthreads();
    for (int o = 1; o < SCH; o <<= 1) {
        int x = (t >= o) ? sd[t - o] : 0; __syncthreads();
        sd[t] += x; __syncthreads();
    }
    if (i < n) rowptr[r * (n + 1) + i] = bsum[r * nch + b] + sd[t] - v;
    if (b == 0 && t == 0) rowptr[r * (n + 1) + n] = NE;
}

__global__ void k_fill(const int* __restrict__ e0, const int* __restrict__ e1,
                       const int* __restrict__ e2, const int* __restrict__ e3,
                       const int* __restrict__ rowptr, const float* __restrict__ dinv,
                       int* __restrict__ fill, int* __restrict__ csr_src,
                       float* __restrict__ csr_coef) {
    const int* es[4] = {e0, e1, e2, e3};
    int r = blockIdx.y;
    int i = blockIdx.x * blockDim.x + threadIdx.x;
    if (i < NE) {
        int s = es[r][i];
        int d = es[r][NE + i];
        int slot = atomicAdd(&fill[r * NN + d], 1);
        int j = rowptr[r * (NN + 1) + d] + slot;
        csr_src[r * NE + j] = s;
        csr_coef[r * NE + j] = dinv[r * NN + s] * dinv[r * NN + d];
    }
}

// ---------------- conversions ----------------

__global__ void k_f2b(const float* __restrict__ in, unsigned short* __restrict__ out, int n4) {
    int i = blockIdx.x * blockDim.x + threadIdx.x;
    if (i < n4) {
        float4 v = ((const float4*)in)[i];
        uint2 o;
        o.x = (unsigned int)f2bf(v.x) | ((unsigned int)f2bf(v.y) << 16);
        o.y = (unsigned int)f2bf(v.z) | ((unsigned int)f2bf(v.w) << 16);
        ((uint2*)out)[i] = o;
    }
}

// W [K x M] fp32 -> Wt [M x K] bf16
__global__ void k_wT(const float* __restrict__ W, unsigned short* __restrict__ Wt, int K, int M) {
    int i = blockIdx.x * blockDim.x + threadIdx.x;
    if (i < K * M) {
        int m = i / K, k = i - m * K;
        Wt[i] = f2bf(W[(size_t)k * M + m]);
    }
}

// ---------------- MFMA GEMM ----------------
// C[nrows x ncols] = A[nrows x K](bf16) * Bt[ncols x K](bf16)^T
// mode 0: store bf16 to outBf
// mode 1: outF = acc + bias[col] + 0.5*(add0+add1)   (fused residual combine)
#define GB_BM 128
#define GB_BN 128
#define GB_BK 32

__global__ __launch_bounds__(256) void k_gemm(
        const unsigned short* __restrict__ A, const unsigned short* __restrict__ Bt,
        int nrows, int K, int ncols,
        unsigned short* __restrict__ outBf, float* __restrict__ outF,
        const float* __restrict__ add0, const float* __restrict__ add1,
        const float* __restrict__ bias, int mode) {
    __shared__ __align__(16) unsigned short As[GB_BM][GB_BK];
    __shared__ __align__(16) unsigned short Bs[GB_BN][GB_BK];
    const int tid = threadIdx.x;
    const int lane = tid & 63;
    const int wid = tid >> 6;
    const int wm = (wid >> 1) * 64;
    const int wn = (wid & 1) * 64;
    const int row0 = blockIdx.x * GB_BM;
    const int col0 = blockIdx.y * GB_BN;
    const int lrow = lane & 15;
    const int lquad = lane >> 4;

    floatx4 acc[4][4];
#pragma unroll
    for (int i = 0; i < 4; i++)
#pragma unroll
        for (int j = 0; j < 4; j++) acc[i][j] = (floatx4){0.f, 0.f, 0.f, 0.f};

    for (int k0 = 0; k0 < K; k0 += GB_BK) {
#pragma unroll
        for (int t = 0; t < 2; t++) {
            int c = tid + t * 256;
            int r = c >> 2;
            int co = (c & 3) * 8;
            int gr = row0 + r; if (gr >= nrows) gr = nrows - 1;
            *(uint4*)&As[r][co] = *(const uint4*)(A + (size_t)gr * K + k0 + co);
            int gc = col0 + r;   // ncols is a multiple of 128 -> always valid
            *(uint4*)&Bs[r][co] = *(const uint4*)(Bt + (size_t)gc * K + k0 + co);
        }
        __syncthreads();
        bf16x8 af[4], bfr[4];
#pragma unroll
        for (int i = 0; i < 4; i++) af[i] = *(const bf16x8*)&As[wm + 16 * i + lrow][lquad * 8];
#pragma unroll
        for (int j = 0; j < 4; j++) bfr[j] = *(const bf16x8*)&Bs[wn + 16 * j + lrow][lquad * 8];
#pragma unroll
        for (int i = 0; i < 4; i++)
#pragma unroll
            for (int j = 0; j < 4; j++)
                acc[i][j] = __builtin_amdgcn_mfma_f32_16x16x32_bf16(af[i], bfr[j], acc[i][j], 0, 0, 0);
        __syncthreads();
    }

#pragma unroll
    for (int i = 0; i < 4; i++) {
#pragma unroll
        for (int j = 0; j < 4; j++) {
            int col = col0 + wn + 16 * j + lrow;
#pragma unroll
            for (int r = 0; r < 4; r++) {
                int row = row0 + wm + 16 * i + lquad * 4 + r;
                if (row < nrows) {
                    float v = acc[i][j][r];
                    size_t idx = (size_t)row * ncols + col;
                    if (mode == 0) {
                        outBf[idx] = f2bf(v);
                    } else {
                        outF[idx] = v + bias[col] + 0.5f * (add0[idx] + add1[idx]);
                    }
                }
            }
        }
    }
}

// ---------------- GCN aggregate (CSR gather) ----------------
// out[i] = lrelu( sum_e coef*xw[src] + xw[i]*invdeg[i] + bias )
// mode 0 -> bf16 outB ; mode 1 -> fp32 outF
template <int NC>
__global__ void k_aggregate(const unsigned short* __restrict__ xw,
                            const int* __restrict__ rowptr,
                            const int* __restrict__ csr_src,
                            const float* __restrict__ csr_coef,
                            const float* __restrict__ invdeg,
                            const float* __restrict__ bias,
                            unsigned short* __restrict__ outB,
                            float* __restrict__ outF, int mode, int n) {
    constexpr int F = NC * 64;
    const int lane = threadIdx.x & 63;
    const int wid = blockIdx.x * (blockDim.x >> 6) + (threadIdx.x >> 6);
    const int nw = gridDim.x * (blockDim.x >> 6);
    const int fb = lane * NC;
    for (int i = wid; i < n; i += nw) {
        float acc[NC];
        float idg = invdeg[i];
        if constexpr (NC == 4) {
            uint2 raw = *(const uint2*)(xw + (size_t)i * F + fb);
            acc[0] = bflo2f(raw.x & 0xffffu) * idg;
            acc[1] = bfhi2f(raw.x) * idg;
            acc[2] = bflo2f(raw.y & 0xffffu) * idg;
            acc[3] = bfhi2f(raw.y) * idg;
            float4 bv = *(const float4*)(bias + fb);
            acc[0] += bv.x; acc[1] += bv.y; acc[2] += bv.z; acc[3] += bv.w;
        } else {
            unsigned int raw = *(const unsigned int*)(xw + (size_t)i * F + fb);
            acc[0] = bflo2f(raw & 0xffffu) * idg;
            acc[1] = bfhi2f(raw) * idg;
            float2 bv = *(const float2*)(bias + fb);
            acc[0] += bv.x; acc[1] += bv.y;
        }
        int e0 = rowptr[i], e1 = rowptr[i + 1];
        int j = e0;
        for (; j + 1 < e1; j += 2) {
            int s0 = csr_src[j], s1 = csr_src[j + 1];
            float c0 = csr_coef[j], c1 = csr_coef[j + 1];
            if constexpr (NC == 4) {
                uint2 r0 = *(const uint2*)(xw + (size_t)s0 * F + fb);
                uint2 r1 = *(const uint2*)(xw + (size_t)s1 * F + fb);
                acc[0] += c0 * bflo2f(r0.x & 0xffffu) + c1 * bflo2f(r1.x & 0xffffu);
                acc[1] += c0 * bfhi2f(r0.x) + c1 * bfhi2f(r1.x);
                acc[2] += c0 * bflo2f(r0.y & 0xffffu) + c1 * bflo2f(r1.y & 0xffffu);
                acc[3] += c0 * bfhi2f(r0.y) + c1 * bfhi2f(r1.y);
            } else {
                unsigned int r0 = *(const unsigned int*)(xw + (size_t)s0 * F + fb);
                unsigned int r1 = *(const unsigned int*)(xw + (size_t)s1 * F + fb);
                acc[0] += c0 * bflo2f(r0 & 0xffffu) + c1 * bflo2f(r1 & 0xffffu);
                acc[1] += c0 * bfhi2f(r0) + c1 * bfhi2f(r1);
            }
        }
        if (j < e1) {
            int s = csr_src[j];
            float cf = csr_coef[j];
            if constexpr (NC == 4) {
                uint2 raw = *(const uint2*)(xw + (size_t)s * F + fb);
                acc[0] += cf * bflo2f(raw.x & 0xffffu);
                acc[1] += cf * bfhi2f(raw.x);
                acc[2] += cf * bflo2f(raw.y & 0xffffu);
                acc[3] += cf * bfhi2f(raw.y);
            } else {
                unsigned int raw = *(const unsigned int*)(xw + (size_t)s * F + fb);
                acc[0] += cf * bflo2f(raw & 0xffffu);
                acc[1] += cf * bfhi2f(raw);
            }
        }
#pragma unroll
        for (int c = 0; c < NC; c++) { float v = acc[c]; acc[c] = v >= 0.f ? v : 0.2f * v; }
        if (mode == 0) {
            if constexpr (NC == 4) {
                uint2 o;
                o.x = (unsigned int)f2bf(acc[0]) | ((unsigned int)f2bf(acc[1]) << 16);
                o.y = (unsigned int)f2bf(acc[2]) | ((unsigned int)f2bf(acc[3]) << 16);
                *(uint2*)(outB + (size_t)i * F + fb) = o;
            } else {
                *(unsigned int*)(outB + (size_t)i * F + fb) =
                    (unsigned int)f2bf(acc[0]) | ((unsigned int)f2bf(acc[1]) << 16);
            }
        } else {
            if constexpr (NC == 4) {
                float4 o = {acc[0], acc[1], acc[2], acc[3]};
                *(float4*)(outF + (size_t)i * F + fb) = o;
            } else {
                float2 o = {acc[0], acc[1]};
                *(float2*)(outF + (size_t)i * F + fb) = o;
            }
        }
    }
}

// ---------------- host launch ----------------

static inline size_t alignup(size_t x) { return (x + 255) & ~(size_t)255; }

extern "C" void kernel_launch(void* const* d_in, const int* in_sizes, int n_in,
                              void* d_out, int out_size, void* d_ws, size_t ws_size,
                              hipStream_t stream) {
    const float* x[4]  = {(const float*)d_in[0], (const float*)d_in[1],
                          (const float*)d_in[2], (const float*)d_in[3]};
    const int* ed[4]   = {(const int*)d_in[4], (const int*)d_in[5],
                          (const int*)d_in[6], (const int*)d_in[7]};
    const float* W1[4] = {(const float*)d_in[8],  (const float*)d_in[10],
                          (const float*)d_in[16], (const float*)d_in[18]};
    const float* b1[4] = {(const float*)d_in[9],  (const float*)d_in[11],
                          (const float*)d_in[17], (const float*)d_in[19]};
    const float* W2[4] = {(const float*)d_in[12], (const float*)d_in[14],
                          (const float*)d_in[20], (const float*)d_in[22]};
    const float* b2[4] = {(const float*)d_in[13], (const float*)d_in[15],
                          (const float*)d_in[21], (const float*)d_in[23]};
    const float* Wr[2] = {(const float*)d_in[24], (const float*)d_in[26]};
    const float* br[2] = {(const float*)d_in[25], (const float*)d_in[27]};

    float* out = (float*)d_out;
    const size_t S = (size_t)NN * 128;   // 6.4M floats per output
    // out slots: 0 comb_l, 1 comb_p, 2 jl, 3 jp, 4 bl, 5 bp

    char* w = (char*)d_ws;
    int*   counts  = (int*)w;                w += alignup((size_t)4 * NN * 4);
    int*   fillp   = (int*)w;                w += alignup((size_t)4 * NN * 4);
    int*   rowptr  = (int*)w;                w += alignup((size_t)4 * (NN + 1) * 4);
    float* dinv    = (float*)w;              w += alignup((size_t)4 * NN * 4);
    float* invdeg  = (float*)w;              w += alignup((size_t)4 * NN * 4);
    int*   bsum    = (int*)w;                w += alignup((size_t)4 * 256 * 4);
    int*   csr_src = (int*)w;                w += alignup((size_t)4 * NE * 4);
    float* csr_cf  = (float*)w;              w += alignup((size_t)4 * NE * 4);
    unsigned short* xbf = (unsigned short*)w;  w += alignup((size_t)NN * 256 * 2);
    unsigned short* xw1 = (unsigned short*)w;  w += alignup((size_t)NN * 256 * 2);
    unsigned short* hbf = (unsigned short*)w;  w += alignup((size_t)NN * 256 * 2);
    unsigned short* xw2 = (unsigned short*)w;  w += alignup((size_t)NN * 128 * 2);
    unsigned short* Wt  = (unsigned short*)w;  w += alignup((size_t)256 * 256 * 2);

    hipMemsetAsync(counts, 0, (size_t)4 * NN * 4, stream);
    hipMemsetAsync(fillp, 0, (size_t)4 * NN * 4, stream);

    dim3 egrid((NE + 255) / 256, 4);
    k_count<<<egrid, 256, 0, stream>>>(ed[0], ed[1], ed[2], ed[3], counts);
    k_deg<<<(4 * NN + 255) / 256, 256, 0, stream>>>(counts, dinv, invdeg, 4 * NN);
    int nch = (NN + SCH - 1) / SCH;
    k_scan_a<<<dim3(nch, 4), SCH, 0, stream>>>(counts, bsum, NN);
    k_scan_b<<<dim3(1, 4), SCH, 0, stream>>>(bsum, nch);
    k_scan_c<<<dim3(nch, 4), SCH, 0, stream>>>(counts, bsum, rowptr, NN, nch);
    k_fill<<<egrid, 256, 0, stream>>>(ed[0], ed[1], ed[2], ed[3], rowptr, dinv,
                                      fillp, csr_src, csr_cf);

    const int gx = (NN + GB_BM - 1) / GB_BM;   // 391
    for (int p = 0; p < 4; p++) {
        const int* rp = rowptr + p * (NN + 1);
        const int* cs = csr_src + (size_t)p * NE;
        const float* cc = csr_cf + (size_t)p * NE;
        const float* idg = invdeg + (size_t)p * NN;

        k_f2b<<<(NN * 256 / 4 + 255) / 256, 256, 0, stream>>>(x[p], xbf, NN * 256 / 4);
        k_wT<<<(256 * 256 + 255) / 256, 256, 0, stream>>>(W1[p], Wt, 256, 256);
        k_gemm<<<dim3(gx, 2), 256, 0, stream>>>(xbf, Wt, NN, 256, 256,
                                                xw1, nullptr, nullptr, nullptr, nullptr, 0);
        k_aggregate<4><<<2048, 256, 0, stream>>>(xw1, rp, cs, cc, idg, b1[p],
                                                 hbf, nullptr, 0, NN);
        k_wT<<<(256 * 128 + 255) / 256, 256, 0, stream>>>(W2[p], Wt, 256, 128);
        k_gemm<<<dim3(gx, 1), 256, 0, stream>>>(hbf, Wt, NN, 256, 128,
                                                xw2, nullptr, nullptr, nullptr, nullptr, 0);
        k_aggregate<2><<<2048, 256, 0, stream>>>(xw2, rp, cs, cc, idg, b2[p],
                                                 nullptr, out + (2 + p) * S, 1, NN);
    }

    for (int t = 0; t < 2; t++) {
        k_f2b<<<(NN * 256 / 4 + 255) / 256, 256, 0, stream>>>(x[t], xbf, NN * 256 / 4);
        k_wT<<<(256 * 128 + 255) / 256, 256, 0, stream>>>(Wr[t], Wt, 256, 128);
        const float* a0 = out + (2 + t) * S;   // jl / jp
        const float* a1 = out + (4 + t) * S;   // bl / bp
        k_gemm<<<dim3(gx, 1), 256, 0, stream>>>(xbf, Wt, NN, 256, 128,
                                                nullptr, out + t * S, a0, a1, br[t], 1);
    }
}

// Round 2
// 1366.712 us; speedup vs baseline: 1.0617x; 1.0617x over previous
//
#include <hip/hip_runtime.h>
#include <cstddef>

#define NN 50000
#define NE 800000

typedef __bf16 bf16x8 __attribute__((ext_vector_type(8)));
typedef float floatx4 __attribute__((ext_vector_type(4)));

__device__ __forceinline__ float bflo2f(unsigned int u) {
    union { unsigned int u; float f; } v; v.u = u << 16; return v.f;
}
__device__ __forceinline__ float bfhi2f(unsigned int u) {
    union { unsigned int u; float f; } v; v.u = u & 0xffff0000u; return v.f;
}
__device__ __forceinline__ unsigned short f2bf(float f) {
    union { float f; unsigned int u; } v; v.f = f;
    unsigned int u = v.u;
    unsigned int r = u + 0x7fffu + ((u >> 16) & 1u);   // RNE
    return (unsigned short)(r >> 16);
}

// ---------------- CSR build ----------------

__global__ void k_count(const int* __restrict__ e0, const int* __restrict__ e1,
                        const int* __restrict__ e2, const int* __restrict__ e3,
                        int* __restrict__ counts) {
    const int* es[4] = {e0, e1, e2, e3};
    int r = blockIdx.y;
    int i = blockIdx.x * blockDim.x + threadIdx.x;
    if (i < NE) {
        int d = es[r][NE + i];
        atomicAdd(&counts[r * NN + d], 1);
    }
}

__global__ void k_deg(const int* __restrict__ counts, float* __restrict__ dinv, int total) {
    int i = blockIdx.x * blockDim.x + threadIdx.x;
    if (i < total) {
        float d = (float)(counts[i] + 1);   // in-deg + self loop
        dinv[i] = rsqrtf(d);
    }
}

#define SCH 256
__global__ void k_scan_a(const int* __restrict__ counts, int* __restrict__ bsum, int n) {
    __shared__ int sd[SCH];
    int r = blockIdx.y, b = blockIdx.x, t = threadIdx.x;
    int i = b * SCH + t;
    int v = (i < n) ? counts[r * n + i] : 0;
    sd[t] = v; __syncthreads();
    for (int o = 1; o < SCH; o <<= 1) {
        int x = (t >= o) ? sd[t - o] : 0; __syncthreads();
        sd[t] += x; __syncthreads();
    }
    if (t == SCH - 1) bsum[r * gridDim.x + b] = sd[t];
}
__global__ void k_scan_b(int* __restrict__ bsum, int nch) {
    __shared__ int sd[SCH];
    int r = blockIdx.y, t = threadIdx.x;
    int v = (t < nch) ? bsum[r * nch + t] : 0;
    sd[t] = v; __syncthreads();
    for (int o = 1; o < SCH; o <<= 1) {
        int x = (t >= o) ? sd[t - o] : 0; __syncthreads();
        sd[t] += x; __syncthreads();
    }
    if (t < nch) bsum[r * nch + t] = sd[t] - v;   // exclusive
}
__global__ void k_scan_c(const int* __restrict__ counts, const int* __restrict__ bsum,
                         int* __restrict__ rowptr, int* __restrict__ rowfill,
                         int n, int nch) {
    __shared__ int sd[SCH];
    int r = blockIdx.y, b = blockIdx.x, t = threadIdx.x;
    int i = b * SCH + t;
    int v = (i < n) ? counts[r * n + i] : 0;
    sd[t] = v; __syncthreads();
    for (int o = 1; o < SCH; o <<= 1) {
        int x = (t >= o) ? sd[t - o] : 0; __syncthreads();
        sd[t] += x; __syncthreads();
    }
    if (i < n) {
        int off = bsum[r * nch + b] + sd[t] - v;
        rowptr[r * (n + 1) + i] = off;
        rowfill[r * n + i] = off;
    }
    if (b == 0 && t == 0) rowptr[r * (n + 1) + n] = NE;
}

// single 4B scatter per edge: csr_src only; slot comes from atomic on rowfill
__global__ void k_fill(const int* __restrict__ e0, const int* __restrict__ e1,
                       const int* __restrict__ e2, const int* __restrict__ e3,
                       int* __restrict__ rowfill, int* __restrict__ csr_src) {
    const int* es[4] = {e0, e1, e2, e3};
    int r = blockIdx.y;
    int i = blockIdx.x * blockDim.x + threadIdx.x;
    if (i < NE) {
        int s = es[r][i];
        int d = es[r][NE + i];
        int j = atomicAdd(&rowfill[r * NN + d], 1);
        csr_src[r * NE + j] = s;
    }
}

// ---------------- batched weight transpose: W[KxM] fp32 -> Wt[MxK] bf16 ----------------

struct WTArgs {
    const float* W[10];
    unsigned short* Wt[10];
    int M[10];   // K is always 256
};

__global__ void k_wT_all(WTArgs a) {
    int g = blockIdx.y;
    int M = a.M[g];
    int total = 256 * M;
    int i = blockIdx.x * blockDim.x + threadIdx.x;
    if (i < total) {
        int m = i >> 8, k = i & 255;        // i = m*256 + k (Wt layout [M x 256])
        a.Wt[g][i] = f2bf(a.W[g][(size_t)k * M + m]);
    }
}

// ---------------- MFMA GEMM ----------------
// C[nrows x ncols] = A[nrows x K] * Bt[ncols x K]^T
// AF32: A is fp32 (converted to bf16 while staging); else A is bf16.
// mode 0: store bf16 to outBf
// mode 1: outF = acc + bias[col] + 0.5*(add0+add1)   (fused residual combine)
#define GB_BM 128
#define GB_BN 128
#define GB_BK 32

template <bool AF32>
__global__ __launch_bounds__(256) void k_gemm(
        const void* __restrict__ Aptr, const unsigned short* __restrict__ Bt,
        int nrows, int K, int ncols,
        unsigned short* __restrict__ outBf, float* __restrict__ outF,
        const float* __restrict__ add0, const float* __restrict__ add1,
        const float* __restrict__ bias, int mode) {
    __shared__ __align__(16) unsigned short As[GB_BM][GB_BK];
    __shared__ __align__(16) unsigned short Bs[GB_BN][GB_BK];
    const int tid = threadIdx.x;
    const int lane = tid & 63;
    const int wid = tid >> 6;
    const int wm = (wid >> 1) * 64;
    const int wn = (wid & 1) * 64;
    const int row0 = blockIdx.x * GB_BM;
    const int col0 = blockIdx.y * GB_BN;
    const int lrow = lane & 15;
    const int lquad = lane >> 4;

    floatx4 acc[4][4];
#pragma unroll
    for (int i = 0; i < 4; i++)
#pragma unroll
        for (int j = 0; j < 4; j++) acc[i][j] = (floatx4){0.f, 0.f, 0.f, 0.f};

    for (int k0 = 0; k0 < K; k0 += GB_BK) {
#pragma unroll
        for (int t = 0; t < 2; t++) {
            int c = tid + t * 256;
            int r = c >> 2;
            int co = (c & 3) * 8;
            int gr = row0 + r; if (gr >= nrows) gr = nrows - 1;
            if constexpr (AF32) {
                const float* pa = (const float*)Aptr + (size_t)gr * K + k0 + co;
                float4 v0 = *(const float4*)pa;
                float4 v1 = *(const float4*)(pa + 4);
                uint4 o;
                o.x = (unsigned int)f2bf(v0.x) | ((unsigned int)f2bf(v0.y) << 16);
                o.y = (unsigned int)f2bf(v0.z) | ((unsigned int)f2bf(v0.w) << 16);
                o.z = (unsigned int)f2bf(v1.x) | ((unsigned int)f2bf(v1.y) << 16);
                o.w = (unsigned int)f2bf(v1.z) | ((unsigned int)f2bf(v1.w) << 16);
                *(uint4*)&As[r][co] = o;
            } else {
                *(uint4*)&As[r][co] =
                    *(const uint4*)((const unsigned short*)Aptr + (size_t)gr * K + k0 + co);
            }
            int gc = col0 + r;   // ncols multiple of 128 -> always valid
            *(uint4*)&Bs[r][co] = *(const uint4*)(Bt + (size_t)gc * K + k0 + co);
        }
        __syncthreads();
        bf16x8 af[4], bfr[4];
#pragma unroll
        for (int i = 0; i < 4; i++) af[i] = *(const bf16x8*)&As[wm + 16 * i + lrow][lquad * 8];
#pragma unroll
        for (int j = 0; j < 4; j++) bfr[j] = *(const bf16x8*)&Bs[wn + 16 * j + lrow][lquad * 8];
#pragma unroll
        for (int i = 0; i < 4; i++)
#pragma unroll
            for (int j = 0; j < 4; j++)
                acc[i][j] = __builtin_amdgcn_mfma_f32_16x16x32_bf16(af[i], bfr[j], acc[i][j], 0, 0, 0);
        __syncthreads();
    }

#pragma unroll
    for (int i = 0; i < 4; i++) {
#pragma unroll
        for (int j = 0; j < 4; j++) {
            int col = col0 + wn + 16 * j + lrow;
#pragma unroll
            for (int r = 0; r < 4; r++) {
                int row = row0 + wm + 16 * i + lquad * 4 + r;
                if (row < nrows) {
                    float v = acc[i][j][r];
                    size_t idx = (size_t)row * ncols + col;
                    if (mode == 0) {
                        outBf[idx] = f2bf(v);
                    } else {
                        outF[idx] = v + bias[col] + 0.5f * (add0[idx] + add1[idx]);
                    }
                }
            }
        }
    }
}

// ---------------- GCN aggregate (CSR gather) ----------------
// out = lrelu( di*( sum_e dinv[s]*xw[s] + di*xw[i] ) + bias ),  di = dinv[i]
// mode 0 -> bf16 outB ; mode 1 -> fp32 outF

__device__ __forceinline__ void ldrow4(const unsigned short* p, float* o) {
    uint2 r = *(const uint2*)p;
    o[0] = bflo2f(r.x & 0xffffu); o[1] = bfhi2f(r.x);
    o[2] = bflo2f(r.y & 0xffffu); o[3] = bfhi2f(r.y);
}
__device__ __forceinline__ void ldrow2(const unsigned short* p, float* o) {
    unsigned int r = *(const unsigned int*)p;
    o[0] = bflo2f(r & 0xffffu); o[1] = bfhi2f(r);
}

template <int NC>
__global__ __launch_bounds__(256) void k_aggregate(
        const unsigned short* __restrict__ xw,
        const int* __restrict__ rowptr,
        const int* __restrict__ cs,
        const float* __restrict__ dinv,
        const float* __restrict__ bias,
        unsigned short* __restrict__ outB,
        float* __restrict__ outF, int mode, int n) {
    constexpr int F = NC * 64;
    const int lane = threadIdx.x & 63;
    const int wid = blockIdx.x * (blockDim.x >> 6) + (threadIdx.x >> 6);
    const int nw = gridDim.x * (blockDim.x >> 6);
    const int fb = lane * NC;

    float bv[NC];
#pragma unroll
    for (int c = 0; c < NC; c++) bv[c] = bias[fb + c];

    for (int i = wid; i < n; i += nw) {
        float di = dinv[i];
        float acc[NC];
        {
            float rv[NC];
            if constexpr (NC == 4) ldrow4(xw + (size_t)i * F + fb, rv);
            else                   ldrow2(xw + (size_t)i * F + fb, rv);
#pragma unroll
            for (int c = 0; c < NC; c++) acc[c] = di * rv[c];
        }
        int e0 = rowptr[i], e1 = rowptr[i + 1];
        int j = e0;
        for (; j + 3 < e1; j += 4) {
            int s0 = cs[j], s1 = cs[j + 1], s2 = cs[j + 2], s3 = cs[j + 3];
            float c0 = dinv[s0], c1 = dinv[s1], c2 = dinv[s2], c3 = dinv[s3];
            float r0[NC], r1[NC], r2[NC], r3[NC];
            if constexpr (NC == 4) {
                ldrow4(xw + (size_t)s0 * F + fb, r0);
                ldrow4(xw + (size_t)s1 * F + fb, r1);
                ldrow4(xw + (size_t)s2 * F + fb, r2);
                ldrow4(xw + (size_t)s3 * F + fb, r3);
            } else {
                ldrow2(xw + (size_t)s0 * F + fb, r0);
                ldrow2(xw + (size_t)s1 * F + fb, r1);
                ldrow2(xw + (size_t)s2 * F + fb, r2);
                ldrow2(xw + (size_t)s3 * F + fb, r3);
            }
#pragma unroll
            for (int c = 0; c < NC; c++)
                acc[c] += c0 * r0[c] + c1 * r1[c] + c2 * r2[c] + c3 * r3[c];
        }
        for (; j < e1; j++) {
            int s = cs[j];
            float cf = dinv[s];
            float rv[NC];
            if constexpr (NC == 4) ldrow4(xw + (size_t)s * F + fb, rv);
            else                   ldrow2(xw + (size_t)s * F + fb, rv);
#pragma unroll
            for (int c = 0; c < NC; c++) acc[c] += cf * rv[c];
        }
#pragma unroll
        for (int c = 0; c < NC; c++) {
            float v = di * acc[c] + bv[c];
            acc[c] = v >= 0.f ? v : 0.2f * v;
        }
        if (mode == 0) {
            if constexpr (NC == 4) {
                uint2 o;
                o.x = (unsigned int)f2bf(acc[0]) | ((unsigned int)f2bf(acc[1]) << 16);
                o.y = (unsigned int)f2bf(acc[2]) | ((unsigned int)f2bf(acc[3]) << 16);
                *(uint2*)(outB + (size_t)i * F + fb) = o;
            } else {
                *(unsigned int*)(outB + (size_t)i * F + fb) =
                    (unsigned int)f2bf(acc[0]) | ((unsigned int)f2bf(acc[1]) << 16);
            }
        } else {
            if constexpr (NC == 4) {
                float4 o = {acc[0], acc[1], acc[2], acc[3]};
                *(float4*)(outF + (size_t)i * F + fb) = o;
            } else {
                float2 o = {acc[0], acc[1]};
                *(float2*)(outF + (size_t)i * F + fb) = o;
            }
        }
    }
}

// ---------------- host launch ----------------

static inline size_t alignup(size_t x) { return (x + 255) & ~(size_t)255; }

extern "C" void kernel_launch(void* const* d_in, const int* in_sizes, int n_in,
                              void* d_out, int out_size, void* d_ws, size_t ws_size,
                              hipStream_t stream) {
    const float* x[4]  = {(const float*)d_in[0], (const float*)d_in[1],
                          (const float*)d_in[2], (const float*)d_in[3]};
    const int* ed[4]   = {(const int*)d_in[4], (const int*)d_in[5],
                          (const int*)d_in[6], (const int*)d_in[7]};
    const float* W1[4] = {(const float*)d_in[8],  (const float*)d_in[10],
                          (const float*)d_in[16], (const float*)d_in[18]};
    const float* b1[4] = {(const float*)d_in[9],  (const float*)d_in[11],
                          (const float*)d_in[17], (const float*)d_in[19]};
    const float* W2[4] = {(const float*)d_in[12], (const float*)d_in[14],
                          (const float*)d_in[20], (const float*)d_in[22]};
    const float* b2[4] = {(const float*)d_in[13], (const float*)d_in[15],
                          (const float*)d_in[21], (const float*)d_in[23]};
    const float* Wr[2] = {(const float*)d_in[24], (const float*)d_in[26]};
    const float* br[2] = {(const float*)d_in[25], (const float*)d_in[27]};

    float* out = (float*)d_out;
    const size_t S = (size_t)NN * 128;
    // out slots: 0 comb_l, 1 comb_p, 2 jl, 3 jp, 4 bl, 5 bp

    char* w = (char*)d_ws;
    int*   counts  = (int*)w;                w += alignup((size_t)4 * NN * 4);
    int*   rowptr  = (int*)w;                w += alignup((size_t)4 * (NN + 1) * 4);
    int*   rowfill = (int*)w;                w += alignup((size_t)4 * NN * 4);
    float* dinv    = (float*)w;              w += alignup((size_t)4 * NN * 4);
    int*   bsum    = (int*)w;                w += alignup((size_t)4 * 256 * 4);
    int*   csr_src = (int*)w;                w += alignup((size_t)4 * NE * 4);
    unsigned short* xw1 = (unsigned short*)w;  w += alignup((size_t)NN * 256 * 2);
    unsigned short* hbf = (unsigned short*)w;  w += alignup((size_t)NN * 256 * 2);
    unsigned short* xw2 = (unsigned short*)w;  w += alignup((size_t)NN * 128 * 2);
    unsigned short* WtA = (unsigned short*)w;  w += alignup((size_t)(4 * 256 * 256 + 6 * 128 * 256) * 2);

    unsigned short* Wt1[4], * Wt2[4], * Wtr[2];
    {
        unsigned short* p = WtA;
        for (int i = 0; i < 4; i++) { Wt1[i] = p; p += 256 * 256; }
        for (int i = 0; i < 4; i++) { Wt2[i] = p; p += 128 * 256; }
        for (int i = 0; i < 2; i++) { Wtr[i] = p; p += 128 * 256; }
    }

    hipMemsetAsync(counts, 0, (size_t)4 * NN * 4, stream);

    dim3 egrid((NE + 255) / 256, 4);
    k_count<<<egrid, 256, 0, stream>>>(ed[0], ed[1], ed[2], ed[3], counts);
    k_deg<<<(4 * NN + 255) / 256, 256, 0, stream>>>(counts, dinv, 4 * NN);
    int nch = (NN + SCH - 1) / SCH;
    k_scan_a<<<dim3(nch, 4), SCH, 0, stream>>>(counts, bsum, NN);
    k_scan_b<<<dim3(1, 4), SCH, 0, stream>>>(bsum, nch);
    k_scan_c<<<dim3(nch, 4), SCH, 0, stream>>>(counts, bsum, rowptr, rowfill, NN, nch);
    k_fill<<<egrid, 256, 0, stream>>>(ed[0], ed[1], ed[2], ed[3], rowfill, csr_src);

    {
        WTArgs a;
        for (int i = 0; i < 4; i++) { a.W[i] = W1[i];     a.Wt[i] = Wt1[i];     a.M[i] = 256; }
        for (int i = 0; i < 4; i++) { a.W[4 + i] = W2[i]; a.Wt[4 + i] = Wt2[i]; a.M[4 + i] = 128; }
        for (int i = 0; i < 2; i++) { a.W[8 + i] = Wr[i]; a.Wt[8 + i] = Wtr[i]; a.M[8 + i] = 128; }
        k_wT_all<<<dim3(256, 10), 256, 0, stream>>>(a);
    }

    const int gx = (NN + GB_BM - 1) / GB_BM;   // 391
    for (int p = 0; p < 4; p++) {
        const int* rp = rowptr + p * (NN + 1);
        const int* cs = csr_src + (size_t)p * NE;
        const float* dv = dinv + (size_t)p * NN;

        k_gemm<true><<<dim3(gx, 2), 256, 0, stream>>>(x[p], Wt1[p], NN, 256, 256,
                xw1, nullptr, nullptr, nullptr, nullptr, 0);
        k_aggregate<4><<<2048, 256, 0, stream>>>(xw1, rp, cs, dv, b1[p],
                hbf, nullptr, 0, NN);
        k_gemm<false><<<dim3(gx, 1), 256, 0, stream>>>(hbf, Wt2[p], NN, 256, 128,
                xw2, nullptr, nullptr, nullptr, nullptr, 0);
        k_aggregate<2><<<2048, 256, 0, stream>>>(xw2, rp, cs, dv, b2[p],
                nullptr, out + (2 + p) * S, 1, NN);
    }

    for (int t = 0; t < 2; t++) {
        const float* a0 = out + (2 + t) * S;   // jl / jp
        const float* a1 = out + (4 + t) * S;   // bl / bp
        k_gemm<true><<<dim3(gx, 1), 256, 0, stream>>>(x[t], Wtr[t], NN, 256, 128,
                nullptr, out + t * S, a0, a1, br[t], 1);
    }
}